// Round 15
// baseline (60.913 us; speedup 1.0000x reference)
//
#include <hip/hip_runtime.h>
#include <hip/hip_bf16.h>

// RBF Gram matrix: out[i][j] = exp(-||X_i - Y_j||^2), X,Y fp32 [8192][256].
// prep: X,Y -> fp8 e4m3 panels (RNE) + fp32 norms.
// gemm64x128 (R15): R14 structure with MX-scaled fp8 MFMA K=128 (scale=1.0,
//   2x MFMA rate). At BM=64, acc=32 VGPRs so MX operands fit the 128-VGPR cap
//   (R8's MX failure was acc=64). Everything else identical to R14: BK=128
//   single-buffer 24KB LDS, 128B rows / XOR-(r&7) swizzle, global_load_lds,
//   B column-permute -> float4 stores, per-XCD traversal, 4 blocks/CU.

#define MROWS 8192
#define NDIM  256
#define BM 64
#define BN 128
#define BK 128
#define NT (NDIM / BK)   // 2

typedef float f32x4 __attribute__((ext_vector_type(4)));
typedef int   i32x8 __attribute__((ext_vector_type(8)));

typedef __attribute__((address_space(1))) const unsigned char gu8;
typedef __attribute__((address_space(3))) unsigned char lu8;

// fp32 -> OCP e4m3fn, RNE, saturating (no NaN inputs expected)
__device__ inline unsigned char f2e4m3(float f) {
    unsigned u = __float_as_uint(f);
    unsigned s = (u >> 24) & 0x80u;
    unsigned au = u & 0x7fffffffu;
    float a = __uint_as_float(au);
    if (a >= 448.0f) return (unsigned char)(s | 0x7E);
    if (a < 0.015625f) {                       // below normal min 2^-6
        float q = a * 512.0f;                  // grid of 2^-9
        int m = (int)rintf(q);                 // 0..8
        return (unsigned char)(s | (unsigned)m);  // m==8 -> 0x08 == 2^-6 normal
    }
    unsigned r = au + 0x7FFFFu + ((au >> 20) & 1u);   // RNE drop 20 bits
    int e = (int)(r >> 23) - 127;              // -6..8 after rounding
    unsigned m3 = (r >> 20) & 7u;
    return (unsigned char)(s | ((unsigned)(e + 7) << 3) | m3);
}

// ---------- prep: fp8 convert + fp32 norms, one wave per row ----------
__global__ __launch_bounds__(256) void rbf_prep(const float* __restrict__ X,
                                                const float* __restrict__ Y,
                                                unsigned char* __restrict__ Xb,
                                                unsigned char* __restrict__ Yb,
                                                float* __restrict__ x2,
                                                float* __restrict__ y2) {
    const int gw   = (blockIdx.x * blockDim.x + threadIdx.x) >> 6;  // 0..16383
    const int lane = threadIdx.x & 63;
    const float* src;
    unsigned char* dstb;
    float* dstn;
    int row;
    if (gw < MROWS) { src = X; dstb = Xb; dstn = x2; row = gw; }
    else            { src = Y; dstb = Yb; dstn = y2; row = gw - MROWS; }

    f32x4 v = *(const f32x4*)(src + (size_t)row * NDIM + lane * 4);
    uchar4 q;
    q.x = f2e4m3(v[0]); q.y = f2e4m3(v[1]); q.z = f2e4m3(v[2]); q.w = f2e4m3(v[3]);
    *(uchar4*)(dstb + (size_t)row * NDIM + lane * 4) = q;

    float ssum = v[0]*v[0] + v[1]*v[1] + v[2]*v[2] + v[3]*v[3];
#pragma unroll
    for (int off = 32; off > 0; off >>= 1) ssum += __shfl_xor(ssum, off);
    if (lane == 0) dstn[row] = ssum;
}

// ---------- 64x128 MX-fp8 GEMM + fused exp, 4 blocks/CU ----------
__global__ __launch_bounds__(256, 4) void rbf_gemm64(
        const unsigned char* __restrict__ Xb,
        const unsigned char* __restrict__ Yb,
        const float* __restrict__ x2,
        const float* __restrict__ y2,
        float* __restrict__ out) {
    // A region: 64 rows x 128B (8 KB). B region: 128 rows x 128B (16 KB).
    __shared__ __align__(16) unsigned char lds[(BM + BN) * BK];  // 24 KiB

    const int tid  = threadIdx.x;
    const int lane = tid & 63;
    const int wid  = tid >> 6;     // 0..3
    const int wy   = wid >> 1;     // 0..1 (32-row half)
    const int wx   = wid & 1;      // 0..1 (64-col half)
    const int fr   = lane & 15;
    const int kh   = lane >> 4;    // 0..3

    // per-XCD traversal (bijective over 8192 blocks)
    const int bid  = blockIdx.x;
    const int xcd  = bid & 7;
    const int idx  = bid >> 3;          // 0..1023
    const int sb   = idx >> 7;          // col-group 0..7
    const int r16  = (idx >> 3) & 15;   // row-tile within band
    const int c8   = idx & 7;           // col-tile within group
    const int row0 = (xcd * 16 + r16) * BM;
    const int col0 = (sb * 8 + c8) * BN;

    const int rr = tid >> 3;                 // 0..31
    const int cc = tid & 7;

    f32x4 acc[2][4] = {};

    for (int t = 0; t < NT; ++t) {
        const int k0 = t * BK;
#pragma unroll
        for (int p = 0; p < 2; ++p) {        // A: rows 0..63
            const int r  = p * 32 + rr;
            const int so = (cc ^ (r & 7)) << 4;
            __builtin_amdgcn_global_load_lds(
                (gu8*)(Xb + (size_t)(row0 + r) * NDIM + k0 + so),
                (lu8*)(lds + p * 4096 + wid * 1024), 16, 0, 0);
        }
#pragma unroll
        for (int p = 0; p < 4; ++p) {        // B: rows 0..127, column-permuted
            const int r  = p * 32 + rr;
            const int pr = (r & 64) | ((r & 15) << 2) | ((r >> 4) & 3);
            const int so = (cc ^ (r & 7)) << 4;
            __builtin_amdgcn_global_load_lds(
                (gu8*)(Yb + (size_t)(col0 + pr) * NDIM + k0 + so),
                (lu8*)(lds + BM * BK + p * 4096 + wid * 1024), 16, 0, 0);
        }
        asm volatile("s_waitcnt vmcnt(0)" ::: "memory");
        __builtin_amdgcn_s_barrier();
        asm volatile("" ::: "memory");

        // MX frag (16x16x128): lane l holds row l&15, k-bytes [(l>>4)*32,+32)
        // -> chunks (2kh)^(r&7), (2kh+1)^(r&7), 16B each.
        const unsigned char* A = lds;
        const unsigned char* B = lds + BM * BK;

        i32x8 bfv[4];
#pragma unroll
        for (int n = 0; n < 4; ++n) {
            const int r  = wx * 64 + n * 16 + fr;
            const int c0 = (2 * kh)     ^ (r & 7);
            const int c1 = (2 * kh + 1) ^ (r & 7);
            const int4 lo = *(const int4*)(B + r * BK + c0 * 16);
            const int4 hi = *(const int4*)(B + r * BK + c1 * 16);
            bfv[n][0] = lo.x; bfv[n][1] = lo.y; bfv[n][2] = lo.z; bfv[n][3] = lo.w;
            bfv[n][4] = hi.x; bfv[n][5] = hi.y; bfv[n][6] = hi.z; bfv[n][7] = hi.w;
        }
        __builtin_amdgcn_s_setprio(1);
#pragma unroll
        for (int m = 0; m < 2; ++m) {
            const int r  = wy * 32 + m * 16 + fr;
            const int c0 = (2 * kh)     ^ (r & 7);
            const int c1 = (2 * kh + 1) ^ (r & 7);
            const int4 lo = *(const int4*)(A + r * BK + c0 * 16);
            const int4 hi = *(const int4*)(A + r * BK + c1 * 16);
            i32x8 af;
            af[0] = lo.x; af[1] = lo.y; af[2] = lo.z; af[3] = lo.w;
            af[4] = hi.x; af[5] = hi.y; af[6] = hi.z; af[7] = hi.w;
#pragma unroll
            for (int n = 0; n < 4; ++n)
                acc[m][n] = __builtin_amdgcn_mfma_scale_f32_16x16x128_f8f6f4(
                    af, bfv[n], acc[m][n],
                    0 /*A fmt: fp8*/, 0 /*B fmt: fp8*/,
                    0, 127 /*scale A = 2^0*/, 0, 127 /*scale B = 2^0*/);
        }
        __builtin_amdgcn_s_setprio(0);
        if (t < NT - 1) {
            asm volatile("" ::: "memory");
            __builtin_amdgcn_s_barrier();
        }
    }

    // ---- epilogue: exp(-(x2 + y2 - 2*xy)), float4 stores ----
    // With B-permute: acc[m][n] -> col = col0 + wx*64 + 4*fr + n (contiguous).
    // Rows: i = row0 + wy*32 + m*16 + kh*4 + rg.
    const int ci = row0 + wy * 32;
    const int cj = col0 + wx * 64 + fr * 4;
    const f32x4 yv = *(const f32x4*)(y2 + cj);
#pragma unroll
    for (int m = 0; m < 2; ++m) {
#pragma unroll
        for (int rg = 0; rg < 4; ++rg) {
            const int i  = ci + m * 16 + kh * 4 + rg;
            const float xi = x2[i];
            f32x4 v;
#pragma unroll
            for (int n = 0; n < 4; ++n) {
                float sq = fmaxf(xi + yv[n] - 2.0f * acc[m][n][rg], 0.0f);
                v[n] = __expf(-sq);
            }
            *(f32x4*)(out + (size_t)i * MROWS + cj) = v;
        }
    }
}

extern "C" void kernel_launch(void* const* d_in, const int* in_sizes, int n_in,
                              void* d_out, int out_size, void* d_ws, size_t ws_size,
                              hipStream_t stream) {
    const float* X = (const float*)d_in[0];
    const float* Y = (const float*)d_in[1];
    float* out = (float*)d_out;

    unsigned char* Xb = (unsigned char*)d_ws;                 // 2 MiB
    unsigned char* Yb = Xb + (size_t)MROWS * NDIM;            // 2 MiB
    float* x2 = (float*)(Yb + (size_t)MROWS * NDIM);
    float* y2 = x2 + MROWS;

    rbf_prep<<<(2 * MROWS) / 4, 256, 0, stream>>>(X, Y, Xb, Yb, x2, y2);

    rbf_gemm64<<<(MROWS / BM) * (MROWS / BN), 256, 0, stream>>>(Xb, Yb, x2, y2, out);
}

// Round 16
// 56.548 us; speedup vs baseline: 1.0772x; 1.0772x over previous
//
#include <hip/hip_runtime.h>
#include <hip/hip_bf16.h>

// RBF Gram matrix: out[i][j] = exp(-||X_i - Y_j||^2), X,Y fp32 [8192][256].
// prep: X,Y -> fp8 e4m3 panels (RNE) + fp32 norms.
// gemm64x128 (R14 final): 64x128 tile (8192 blocks, 8 generations, 4/CU).
//   BK=128 single-buffer 24KB LDS, 128B rows / 8x16B chunks / XOR-(r&7)
//   swizzle, global_load_lds w=16 pre-swizzled source, fp8 MFMA 16x16x32,
//   B column-permute -> float4 epilogue stores, per-XCD traversal.
// (R15's MX variant regressed 60.9 vs 56.8 -> reverted to proven best.)

#define MROWS 8192
#define NDIM  256
#define BM 64
#define BN 128
#define BK 128
#define NT (NDIM / BK)   // 2

typedef float f32x4 __attribute__((ext_vector_type(4)));

typedef __attribute__((address_space(1))) const unsigned char gu8;
typedef __attribute__((address_space(3))) unsigned char lu8;

// fp32 -> OCP e4m3fn, RNE, saturating (no NaN inputs expected)
__device__ inline unsigned char f2e4m3(float f) {
    unsigned u = __float_as_uint(f);
    unsigned s = (u >> 24) & 0x80u;
    unsigned au = u & 0x7fffffffu;
    float a = __uint_as_float(au);
    if (a >= 448.0f) return (unsigned char)(s | 0x7E);
    if (a < 0.015625f) {                       // below normal min 2^-6
        float q = a * 512.0f;                  // grid of 2^-9
        int m = (int)rintf(q);                 // 0..8
        return (unsigned char)(s | (unsigned)m);  // m==8 -> 0x08 == 2^-6 normal
    }
    unsigned r = au + 0x7FFFFu + ((au >> 20) & 1u);   // RNE drop 20 bits
    int e = (int)(r >> 23) - 127;              // -6..8 after rounding
    unsigned m3 = (r >> 20) & 7u;
    return (unsigned char)(s | ((unsigned)(e + 7) << 3) | m3);
}

// ---------- prep: fp8 convert + fp32 norms, one wave per row ----------
__global__ __launch_bounds__(256) void rbf_prep(const float* __restrict__ X,
                                                const float* __restrict__ Y,
                                                unsigned char* __restrict__ Xb,
                                                unsigned char* __restrict__ Yb,
                                                float* __restrict__ x2,
                                                float* __restrict__ y2) {
    const int gw   = (blockIdx.x * blockDim.x + threadIdx.x) >> 6;  // 0..16383
    const int lane = threadIdx.x & 63;
    const float* src;
    unsigned char* dstb;
    float* dstn;
    int row;
    if (gw < MROWS) { src = X; dstb = Xb; dstn = x2; row = gw; }
    else            { src = Y; dstb = Yb; dstn = y2; row = gw - MROWS; }

    f32x4 v = *(const f32x4*)(src + (size_t)row * NDIM + lane * 4);
    uchar4 q;
    q.x = f2e4m3(v[0]); q.y = f2e4m3(v[1]); q.z = f2e4m3(v[2]); q.w = f2e4m3(v[3]);
    *(uchar4*)(dstb + (size_t)row * NDIM + lane * 4) = q;

    float ssum = v[0]*v[0] + v[1]*v[1] + v[2]*v[2] + v[3]*v[3];
#pragma unroll
    for (int off = 32; off > 0; off >>= 1) ssum += __shfl_xor(ssum, off);
    if (lane == 0) dstn[row] = ssum;
}

// ---------- 64x128 fp8 GEMM + fused exp, 4 blocks/CU ----------
__global__ __launch_bounds__(256, 4) void rbf_gemm64(
        const unsigned char* __restrict__ Xb,
        const unsigned char* __restrict__ Yb,
        const float* __restrict__ x2,
        const float* __restrict__ y2,
        float* __restrict__ out) {
    // A region: 64 rows x 128B (8 KB). B region: 128 rows x 128B (16 KB).
    __shared__ __align__(16) unsigned char lds[(BM + BN) * BK];  // 24 KiB

    const int tid  = threadIdx.x;
    const int lane = tid & 63;
    const int wid  = tid >> 6;     // 0..3
    const int wy   = wid >> 1;     // 0..1 (32-row half)
    const int wx   = wid & 1;      // 0..1 (64-col half)
    const int fr   = lane & 15;
    const int kh   = lane >> 4;    // 0..3

    // per-XCD traversal (bijective over 8192 blocks): xcd owns 16 row-tiles;
    // col-groups of 8 processed in sequence -> ~512KB/XCD working set.
    const int bid  = blockIdx.x;
    const int xcd  = bid & 7;
    const int idx  = bid >> 3;          // 0..1023
    const int sb   = idx >> 7;          // col-group 0..7
    const int r16  = (idx >> 3) & 15;   // row-tile within band
    const int c8   = idx & 7;           // col-tile within group
    const int row0 = (xcd * 16 + r16) * BM;
    const int col0 = (sb * 8 + c8) * BN;

    // staging: 1536 x 16B chunks per k-tile, 6 per thread.
    const int rr = tid >> 3;                 // 0..31
    const int cc = tid & 7;

    f32x4 acc[2][4] = {};

    for (int t = 0; t < NT; ++t) {
        const int k0 = t * BK;
#pragma unroll
        for (int p = 0; p < 2; ++p) {        // A: rows 0..63
            const int r  = p * 32 + rr;
            const int so = (cc ^ (r & 7)) << 4;
            __builtin_amdgcn_global_load_lds(
                (gu8*)(Xb + (size_t)(row0 + r) * NDIM + k0 + so),
                (lu8*)(lds + p * 4096 + wid * 1024), 16, 0, 0);
        }
#pragma unroll
        for (int p = 0; p < 4; ++p) {        // B: rows 0..127, column-permuted
            const int r  = p * 32 + rr;
            const int pr = (r & 64) | ((r & 15) << 2) | ((r >> 4) & 3);
            const int so = (cc ^ (r & 7)) << 4;
            __builtin_amdgcn_global_load_lds(
                (gu8*)(Yb + (size_t)(col0 + pr) * NDIM + k0 + so),
                (lu8*)(lds + BM * BK + p * 4096 + wid * 1024), 16, 0, 0);
        }
        asm volatile("s_waitcnt vmcnt(0)" ::: "memory");
        __builtin_amdgcn_s_barrier();
        asm volatile("" ::: "memory");

        const unsigned char* A = lds;
        const unsigned char* B = lds + BM * BK;
        const int j2 = kh >> 1;
        const int h8 = (kh & 1) * 8;
#pragma unroll
        for (int s = 0; s < 4; ++s) {        // four K=32 steps in BK=128
            long bfv[4];
#pragma unroll
            for (int n = 0; n < 4; ++n) {
                const int r  = wx * 64 + n * 16 + fr;
                const int ch = (2 * s + j2) ^ (r & 7);
                bfv[n] = *(const long*)(B + r * BK + ch * 16 + h8);
            }
            __builtin_amdgcn_s_setprio(1);
#pragma unroll
            for (int m = 0; m < 2; ++m) {
                const int r  = wy * 32 + m * 16 + fr;
                const int ch = (2 * s + j2) ^ (r & 7);
                long af = *(const long*)(A + r * BK + ch * 16 + h8);
#pragma unroll
                for (int n = 0; n < 4; ++n)
                    acc[m][n] = __builtin_amdgcn_mfma_f32_16x16x32_fp8_fp8(
                        af, bfv[n], acc[m][n], 0, 0, 0);
            }
            __builtin_amdgcn_s_setprio(0);
        }
        if (t < NT - 1) {
            asm volatile("" ::: "memory");
            __builtin_amdgcn_s_barrier();
        }
    }

    // ---- epilogue: exp(-(x2 + y2 - 2*xy)), float4 stores ----
    // With B-permute: acc[m][n] -> col = col0 + wx*64 + 4*fr + n (contiguous).
    // Rows: i = row0 + wy*32 + m*16 + kh*4 + rg.
    const int ci = row0 + wy * 32;
    const int cj = col0 + wx * 64 + fr * 4;
    const f32x4 yv = *(const f32x4*)(y2 + cj);
#pragma unroll
    for (int m = 0; m < 2; ++m) {
#pragma unroll
        for (int rg = 0; rg < 4; ++rg) {
            const int i  = ci + m * 16 + kh * 4 + rg;
            const float xi = x2[i];
            f32x4 v;
#pragma unroll
            for (int n = 0; n < 4; ++n) {
                float sq = fmaxf(xi + yv[n] - 2.0f * acc[m][n][rg], 0.0f);
                v[n] = __expf(-sq);
            }
            *(f32x4*)(out + (size_t)i * MROWS + cj) = v;
        }
    }
}

extern "C" void kernel_launch(void* const* d_in, const int* in_sizes, int n_in,
                              void* d_out, int out_size, void* d_ws, size_t ws_size,
                              hipStream_t stream) {
    const float* X = (const float*)d_in[0];
    const float* Y = (const float*)d_in[1];
    float* out = (float*)d_out;

    unsigned char* Xb = (unsigned char*)d_ws;                 // 2 MiB
    unsigned char* Yb = Xb + (size_t)MROWS * NDIM;            // 2 MiB
    float* x2 = (float*)(Yb + (size_t)MROWS * NDIM);
    float* y2 = x2 + MROWS;

    rbf_prep<<<(2 * MROWS) / 4, 256, 0, stream>>>(X, Y, Xb, Yb, x2, y2);

    rbf_gemm64<<<(MROWS / BM) * (MROWS / BN), 256, 0, stream>>>(Xb, Yb, x2, y2, out);
}